// Round 3
// baseline (279.994 us; speedup 1.0000x reference)
//
#include <hip/hip_runtime.h>

#define NCACHE 384
#define NSEL   128

__device__ __forceinline__ unsigned int sortable_bits(float f) {
    unsigned int u = __float_as_uint(f);
    return (u & 0x80000000u) ? ~u : (u | 0x80000000u);
}

__global__ __launch_bounds__(128) void select_kernel(
    const float* __restrict__ cache,    // (384, 5): dir.x dir.y dir.z mip bright
    const float* __restrict__ refdirs,  // (B, 3)
    const float* __restrict__ normal,   // (B, 3)
    float* __restrict__ out,            // rays (B,256,3) then mipval (B,256)
    int B)
{
#pragma clang fp contract(off)
    __shared__ float sdx[NCACHE], sdy[NCACHE], sdz[NCACHE], smip[NCACHE];
    __shared__ unsigned long long keys[NCACHE];
    __shared__ unsigned int bitmap[12];

    const int b   = blockIdx.x;
    const int tid = threadIdx.x;

    // Stage cache into LDS
    for (int m = tid; m < NCACHE; m += 128) {
        sdx[m]  = cache[m * 5 + 0];
        sdy[m]  = cache[m * 5 + 1];
        sdz[m]  = cache[m * 5 + 2];
        smip[m] = cache[m * 5 + 3];
    }
    if (tid < 12) bitmap[tid] = 0u;

    const float nx = normal[b * 3 + 0], ny = normal[b * 3 + 1], nz = normal[b * 3 + 2];
    const float rx = refdirs[b * 3 + 0], ry = refdirs[b * 3 + 1], rz = refdirs[b * 3 + 2];

    __syncthreads();

    // Scores -> stable-sort keys (value asc, index asc).
    // Dot products as explicit FMA left-chains (XLA/BLAS-style accumulation:
    // c = fma(a_k, b_k, c) over k, with fma(a0,b0,0) == a0*b0 exactly).
    // -0.0 canonicalized to +0.0 (ties equal under float ==).
    for (int m = tid; m < NCACHE; m += 128) {
        float dx = sdx[m], dy = sdy[m], dz = sdz[m];
        float hemi = __builtin_fmaf(nz, dz, __builtin_fmaf(ny, dy, nx * dx));
        float sim  = __builtin_fmaf(rz, dz, __builtin_fmaf(ry, dy, rx * dx));
        float val  = (hemi > 0.0f) ? -sim : 0.0f;
        val = val + 0.0f;
        keys[m] = ((unsigned long long)sortable_bits(val) << 32) | (unsigned int)m;
    }
    __syncthreads();

    // Each thread m = tid (< 128): stable rank among all 384 scores.
    const unsigned long long mykey = keys[tid];
    int r = 0;
#pragma unroll 8
    for (int j = 0; j < NCACHE; ++j) {
        r += (keys[j] < mykey) ? 1 : 0;
    }

    // Ranks of the 128 elements are distinct values in [0, 384).
    // Output slot k = #{ranks < r}, via bitmap + popcount.
    atomicOr(&bitmap[r >> 5], 1u << (r & 31));
    __syncthreads();

    const int wi = r >> 5;
    int k = __popc(bitmap[wi] & ((1u << (r & 31)) - 1u));
    for (int w = 0; w < wi; ++w) k += __popc(bitmap[w]);

    // sel_rays[k] = cache_dirs[r]; sel_mip[k] = cache_mip[r]  (r = sorted position)
    float* out_rays = out;
    float* out_mip  = out + (size_t)B * 768;
    const size_t rb = (size_t)b * 768 + 384 + (size_t)k * 3;
    out_rays[rb + 0] = sdx[r];
    out_rays[rb + 1] = sdy[r];
    out_rays[rb + 2] = sdz[r];
    out_mip[(size_t)b * 256 + 128 + k] = smip[r];
}

// samp_rays (B,128,3) -> out rays rows [0,128): per b, 96 float4 -> row offset b*192 f4
__global__ void copy_rays_kernel(const float4* __restrict__ src, float4* __restrict__ dst, int n4) {
    int i = blockIdx.x * blockDim.x + threadIdx.x;
    const int stride = gridDim.x * blockDim.x;
    for (; i < n4; i += stride) {
        int b = i / 96;
        int j = i - b * 96;
        dst[b * 192 + j] = src[i];
    }
}

// samp_mipval (B,128) -> out mip rows [0,128): per b, 32 float4 -> row offset b*64 f4
__global__ void copy_mip_kernel(const float4* __restrict__ src, float4* __restrict__ dst, int n4) {
    int i = blockIdx.x * blockDim.x + threadIdx.x;
    const int stride = gridDim.x * blockDim.x;
    for (; i < n4; i += stride) {
        int b = i >> 5;
        int j = i & 31;
        dst[b * 64 + j] = src[i];
    }
}

extern "C" void kernel_launch(void* const* d_in, const int* in_sizes, int n_in,
                              void* d_out, int out_size, void* d_ws, size_t ws_size,
                              hipStream_t stream) {
    const float* cache       = (const float*)d_in[0];
    const float* refdirs     = (const float*)d_in[1];
    const float* normal      = (const float*)d_in[2];
    const float* samp_rays   = (const float*)d_in[3];
    const float* samp_mipval = (const float*)d_in[4];
    float* out = (float*)d_out;

    const int B = in_sizes[1] / 3;  // 65536

    select_kernel<<<B, 128, 0, stream>>>(cache, refdirs, normal, out, B);

    const int n4r = B * 96;  // 25165824 floats / 4
    copy_rays_kernel<<<2048, 256, 0, stream>>>((const float4*)samp_rays, (float4*)out, n4r);

    const int n4m = B * 32;  // 8388608 floats / 4
    copy_mip_kernel<<<2048, 256, 0, stream>>>((const float4*)samp_mipval,
                                              (float4*)(out + (size_t)B * 768), n4m);
}

// Round 4
// 208.736 us; speedup vs baseline: 1.3414x; 1.3414x over previous
//
#include <hip/hip_runtime.h>

#define NCACHE 384
#define NSEL   128

__device__ __forceinline__ unsigned int sortable_bits(float f) {
    unsigned int u = __float_as_uint(f);
    return (u & 0x80000000u) ? ~u : (u | 0x80000000u);
}

struct __align__(16) u64x2 { unsigned long long x, y; };

// 256 threads = 4 waves; wave w handles b = blockIdx.x*4 + w entirely.
__global__ __launch_bounds__(256) void fused_kernel(
    const float*  __restrict__ cache,        // (384,5)
    const float*  __restrict__ refdirs,      // (B,3)
    const float*  __restrict__ normal,       // (B,3)
    const float4* __restrict__ samp_rays4,   // B*96 float4
    const float4* __restrict__ samp_mip4,    // B*32 float4
    float* __restrict__ out, int B)
{
#pragma clang fp contract(off)
    __shared__ float sdx[NCACHE], sdy[NCACHE], sdz[NCACHE], smip[NCACHE];
    __shared__ __align__(16) unsigned long long keys[4][NCACHE];
    __shared__ unsigned int bitmap[4][12];

    const int tid  = threadIdx.x;
    const int wave = tid >> 6;
    const int lane = tid & 63;
    const int b    = blockIdx.x * 4 + wave;

    // Stage cache into LDS (cooperative, once per block)
    for (int m = tid; m < NCACHE; m += 256) {
        sdx[m]  = cache[m * 5 + 0];
        sdy[m]  = cache[m * 5 + 1];
        sdz[m]  = cache[m * 5 + 2];
        smip[m] = cache[m * 5 + 3];
    }
    if (tid < 48) (&bitmap[0][0])[tid] = 0u;

    const float nx = normal[b * 3 + 0], ny = normal[b * 3 + 1], nz = normal[b * 3 + 2];
    const float rx = refdirs[b * 3 + 0], ry = refdirs[b * 3 + 1], rz = refdirs[b * 3 + 2];

    __syncthreads();

    // Scores -> stable keys (FMA left-chains, bit-exact vs reference; -0.0 -> +0.0)
    for (int m = lane; m < NCACHE; m += 64) {
        float dx = sdx[m], dy = sdy[m], dz = sdz[m];
        float hemi = __builtin_fmaf(nz, dz, __builtin_fmaf(ny, dy, nx * dx));
        float sim  = __builtin_fmaf(rz, dz, __builtin_fmaf(ry, dy, rx * dx));
        float val  = (hemi > 0.0f) ? -sim : 0.0f;
        val = val + 0.0f;
        keys[wave][m] = ((unsigned long long)sortable_bits(val) << 32) | (unsigned int)m;
    }
    __syncthreads();

    // Stable ranks for the 128 elements m<128: lane handles m0=lane, m1=lane+64.
    const unsigned long long k0 = keys[wave][lane];
    const unsigned long long k1 = keys[wave][lane + 64];
    const u64x2* kp = (const u64x2*)&keys[wave][0];
    int r0 = 0, r1 = 0;
#pragma unroll 8
    for (int j = 0; j < NCACHE / 2; ++j) {
        u64x2 kk = kp[j];
        r0 += (kk.x < k0) ? 1 : 0;
        r0 += (kk.y < k0) ? 1 : 0;
        r1 += (kk.x < k1) ? 1 : 0;
        r1 += (kk.y < k1) ? 1 : 0;
    }

    // Ranks are distinct in [0,384). Output slot = #{selected ranks < r}.
    atomicOr(&bitmap[wave][r0 >> 5], 1u << (r0 & 31));
    atomicOr(&bitmap[wave][r1 >> 5], 1u << (r1 & 31));
    __syncthreads();

    float* out_rays = out;
    float* out_mip  = out + (size_t)B * 768;

    {
        const int wi = r0 >> 5;
        int s = __popc(bitmap[wave][wi] & ((1u << (r0 & 31)) - 1u));
        for (int w = 0; w < wi; ++w) s += __popc(bitmap[wave][w]);
        const size_t rb = (size_t)b * 768 + 384 + (size_t)s * 3;
        out_rays[rb + 0] = sdx[r0];
        out_rays[rb + 1] = sdy[r0];
        out_rays[rb + 2] = sdz[r0];
        out_mip[(size_t)b * 256 + 128 + s] = smip[r0];
    }
    {
        const int wi = r1 >> 5;
        int s = __popc(bitmap[wave][wi] & ((1u << (r1 & 31)) - 1u));
        for (int w = 0; w < wi; ++w) s += __popc(bitmap[wave][w]);
        const size_t rb = (size_t)b * 768 + 384 + (size_t)s * 3;
        out_rays[rb + 0] = sdx[r1];
        out_rays[rb + 1] = sdy[r1];
        out_rays[rb + 2] = sdz[r1];
        out_mip[(size_t)b * 256 + 128 + s] = smip[r1];
    }

    // Fused pass-through copies for this block's 4 b values:
    // rays: 96 f4 per b -> out f4 row b*192 (+0..95); mip: 32 f4 per b -> mip f4 row b*64 (+0..31)
    float4* out4     = (float4*)out;
    float4* out_mip4 = (float4*)(out + (size_t)B * 768);
    const int b0 = blockIdx.x * 4;
#pragma unroll
    for (int i = tid; i < 512; i += 256) {
        const int bw  = i >> 7;
        const int off = i & 127;
        const int bb  = b0 + bw;
        if (off < 96) {
            out4[(size_t)bb * 192 + off] = samp_rays4[(size_t)bb * 96 + off];
        } else {
            out_mip4[(size_t)bb * 64 + (off - 96)] = samp_mip4[(size_t)bb * 32 + (off - 96)];
        }
    }
}

extern "C" void kernel_launch(void* const* d_in, const int* in_sizes, int n_in,
                              void* d_out, int out_size, void* d_ws, size_t ws_size,
                              hipStream_t stream) {
    const float* cache       = (const float*)d_in[0];
    const float* refdirs     = (const float*)d_in[1];
    const float* normal      = (const float*)d_in[2];
    const float* samp_rays   = (const float*)d_in[3];
    const float* samp_mipval = (const float*)d_in[4];
    float* out = (float*)d_out;

    const int B = in_sizes[1] / 3;  // 65536

    fused_kernel<<<B / 4, 256, 0, stream>>>(cache, refdirs, normal,
                                            (const float4*)samp_rays,
                                            (const float4*)samp_mipval,
                                            out, B);
}